// Round 3
// baseline (316.754 us; speedup 1.0000x reference)
//
#include <hip/hip_runtime.h>
#include <math.h>

// Linear attention forward, bf16-MFMA, pipelined (T14) + in-register fragments.
// B=8, L=S=8192, D=256, H=8, hd=32.

#define B_ 8
#define S_ 8192
#define D_ 256
#define H_ 8
#define EPS_ 1e-6f

typedef short short8 __attribute__((ext_vector_type(8)));
typedef float f32x16 __attribute__((ext_vector_type(16)));

// kA LDS: ldsK 32K | ldsV 32K | masks 512B
#define KA_K 0
#define KA_V 32768
#define KA_M 65536
#define KA_BYTES 66048
// kB LDS: ldsQ 32K | ldsO(voF) 32K | masks 512B | Ksum 1K | bq 1K
#define KB_Q 0
#define KB_O 32768
#define KB_M 65536
#define KB_S 66048
#define KB_BQ 67072
#define KB_BYTES 68096

static __device__ __forceinline__ unsigned short f2bf(float f) {
  union { float f; unsigned u; } v; v.f = f;
  return (unsigned short)((v.u + 0x7fffu + ((v.u >> 16) & 1u)) >> 16);
}
static __device__ __forceinline__ unsigned pack2(float a, float b) {
  return (unsigned)f2bf(a) | ((unsigned)f2bf(b) << 16);
}

// ---- staging: issue-early (global->reg), write-late (reg->LDS bf16 chunks) ----
// chunk c = g*64 + (tok ^ (g&31)); entry 16B = X[tok][8g..8g+7] (bf16).
static __device__ __forceinline__ void stage_issue(const float* __restrict__ src,
                                                   int tid, float4* R) {
  const float4* s4 = (const float4*)src;
#pragma unroll
  for (int i = 0; i < 16; ++i) R[i] = s4[i * 256 + tid];
}
static __device__ __forceinline__ void stage_write(char* __restrict__ dst,
                                                   int tid, const float4* R) {
  const int w = tid >> 6, lane = tid & 63, g = lane >> 1, j = lane & 1;
#pragma unroll
  for (int i = 0; i < 16; ++i) {
    const int tok = 4 * i + w;
    *(ushort4*)(dst + ((g * 64 + (tok ^ (g & 31))) * 16 + j * 8)) =
        make_ushort4(f2bf(R[i].x), f2bf(R[i].y), f2bf(R[i].z), f2bf(R[i].w));
  }
}

// Build an MFMA A/B fragment (k = 8*kg + j over a 16-slice) from epilogue words.
// wQc = packed word at q = 2*sel + Q, c; own half + partner half via shfl_xor(32).
static __device__ __forceinline__ short8 mk_frag(unsigned w00, unsigned w01,
                                                 unsigned w10, unsigned w11, int kg) {
  unsigned a0 = kg ? w10 : w00, a1 = kg ? w11 : w01;   // own W[2sel+kg][c]
  unsigned s0 = kg ? w00 : w10, s1 = kg ? w01 : w11;   // send W[2sel+1-kg][c]
  unsigned r0 = __shfl_xor(s0, 32), r1 = __shfl_xor(s1, 32); // recv W[2sel+kg][c]
  union { unsigned u[4]; short8 s8; } f;
  f.u[0] = kg ? r0 : a0; f.u[1] = kg ? r1 : a1;
  f.u[2] = kg ? a0 : r0; f.u[3] = kg ? a1 : r1;
  return f.s8;
}

// D[tok][o] = X(lds chunks) @ W^T(frag-major global). acc[mt][nt].
template <bool XOR>
static __device__ __forceinline__ void gemm_std(const char* __restrict__ ldsX,
                                                const short8* __restrict__ Wf,
                                                int w, int lo, int kg, f32x16 acc[2][2]) {
#pragma unroll
  for (int a = 0; a < 2; ++a)
#pragma unroll
    for (int c = 0; c < 2; ++c)
#pragma unroll
      for (int i = 0; i < 16; ++i) acc[a][c][i] = 0.f;
#pragma unroll 4
  for (int ks = 0; ks < 16; ++ks) {
    const int g = 2 * ks + kg;
    short8 af[2], bf[2];
#pragma unroll
    for (int mt = 0; mt < 2; ++mt) {
      int tok = mt * 32 + lo;
      if (XOR) tok ^= (g & 31);
      af[mt] = *(const short8*)(ldsX + (g * 64 + tok) * 16);
    }
#pragma unroll
    for (int nt = 0; nt < 2; ++nt) bf[nt] = Wf[g * 256 + w * 64 + nt * 32 + lo];
#pragma unroll
    for (int mt = 0; mt < 2; ++mt)
#pragma unroll
      for (int nt = 0; nt < 2; ++nt)
        acc[mt][nt] = __builtin_amdgcn_mfma_f32_32x32x16_bf16(af[mt], bf[nt],
                                                              acc[mt][nt], 0, 0, 0);
  }
}

// D[o][tok] = W @ X^T (flipped). acc[At][Bt].
static __device__ __forceinline__ void gemm_flip(const char* __restrict__ ldsX,
                                                 const short8* __restrict__ Wf,
                                                 int w, int lo, int kg, f32x16 acc[2][2]) {
#pragma unroll
  for (int a = 0; a < 2; ++a)
#pragma unroll
    for (int c = 0; c < 2; ++c)
#pragma unroll
      for (int i = 0; i < 16; ++i) acc[a][c][i] = 0.f;
#pragma unroll 4
  for (int ks = 0; ks < 16; ++ks) {
    const int g = 2 * ks + kg;
    short8 aw[2], bx[2];
#pragma unroll
    for (int At = 0; At < 2; ++At) aw[At] = Wf[g * 256 + w * 64 + At * 32 + lo];
#pragma unroll
    for (int Bt = 0; Bt < 2; ++Bt)
      bx[Bt] = *(const short8*)(ldsX + (g * 64 + ((Bt * 32 + lo) ^ (g & 31))) * 16);
#pragma unroll
    for (int At = 0; At < 2; ++At)
#pragma unroll
      for (int Bt = 0; Bt < 2; ++Bt)
        acc[At][Bt] = __builtin_amdgcn_mfma_f32_32x32x16_bf16(aw[At], bx[Bt],
                                                              acc[At][Bt], 0, 0, 0);
  }
}

__global__ void kPrep(const float* __restrict__ Wq, const float* __restrict__ Wk,
                      const float* __restrict__ Wv, const float* __restrict__ Wm,
                      unsigned short* __restrict__ Wf) {
  int idx = blockIdx.x * 256 + threadIdx.x;  // 32768 = 4*32*256
  int wsel = idx >> 13, g = (idx >> 8) & 31, o = idx & 255;
  const float* W = wsel == 0 ? Wq : wsel == 1 ? Wk : wsel == 2 ? Wv : Wm;
  const float* p = W + o * 256 + g * 8;
  *(ushort4*)(Wf + (size_t)idx * 8) =
      make_ushort4(f2bf(p[0]), f2bf(p[1]), f2bf(p[2]), f2bf(p[3]));
  *(ushort4*)(Wf + (size_t)idx * 8 + 4) =
      make_ushort4(f2bf(p[4]), f2bf(p[5]), f2bf(p[6]), f2bf(p[7]));
}

// kA: K/V projections + feature map + KV/Ksum partials. grid (64, B_), 256 thr.
__global__ void __launch_bounds__(256, 2)
kA(const float* __restrict__ keys, const float* __restrict__ values,
   const float* __restrict__ kmask,
   const float* __restrict__ bk, const float* __restrict__ bv,
   const short8* __restrict__ WfK, const short8* __restrict__ WfV,
   float* __restrict__ kvpart, float* __restrict__ kspart,
   float* __restrict__ KV, float* __restrict__ Ksum, int use_atomic) {
  extern __shared__ char lds[];
  char* ldsK = lds + KA_K;
  char* ldsV = lds + KA_V;
  float* ldsM = (float*)(lds + KA_M);
  const int tid = threadIdx.x, w = tid >> 6, lane = tid & 63, lo = lane & 31, kg = lane >> 5;
  const int blk = blockIdx.x, b = blockIdx.y;
  const size_t base = ((size_t)b * S_ + blk * 128) * D_;

  const float bk0 = bk[w * 64 + lo], bk1 = bk[w * 64 + 32 + lo];
  const float bv0 = bv[w * 64 + lo], bv1 = bv[w * 64 + 32 + lo];

  f32x16 kvacc[2];
#pragma unroll
  for (int hh = 0; hh < 2; ++hh)
#pragma unroll
    for (int i = 0; i < 16; ++i) kvacc[hh][i] = 0.f;
  float ks0 = 0.f, ks1 = 0.f;

  float4 RK[16], RV[16];
  stage_issue(keys + base, tid, RK);
  stage_issue(values + base, tid, RV);
  if (tid < 128) ldsM[tid] = kmask[(size_t)b * S_ + blk * 128 + tid];
  stage_write(ldsK, tid, RK);

#pragma unroll
  for (int it = 0; it < 2; ++it) {
    __syncthreads();  // ldsK(it) + masks visible
    f32x16 acc[2][2];
    gemm_std<true>(ldsK, WfK, w, lo, kg, acc);

    // K epilogue: bias + elu+1 + mask -> packed words + Ksum partial
    unsigned Wk_[2][2][4][2];
#pragma unroll
    for (int mt = 0; mt < 2; ++mt)
#pragma unroll
      for (int nt = 0; nt < 2; ++nt) {
        const float bias = nt ? bk1 : bk0;
#pragma unroll
        for (int q = 0; q < 4; ++q) {
          float vv[4];
#pragma unroll
          for (int c = 0; c < 4; ++c) {
            const int tok = it * 64 + 32 * mt + 8 * q + 4 * kg + c;
            float f = acc[mt][nt][4 * q + c] + bias;
            f = f > 0.f ? f + 1.f : __expf(f);
            f *= ldsM[tok];
            if (nt == 0) ks0 += f; else ks1 += f;
            vv[c] = f;
          }
          Wk_[mt][nt][q][0] = pack2(vv[0], vv[1]);
          Wk_[mt][nt][q][1] = pack2(vv[2], vv[3]);
        }
      }
    short8 kf[2][4];
#pragma unroll
    for (int nt = 0; nt < 2; ++nt)
#pragma unroll
      for (int mt = 0; mt < 2; ++mt)
#pragma unroll
        for (int sel = 0; sel < 2; ++sel)
          kf[nt][2 * mt + sel] = mk_frag(Wk_[mt][nt][2 * sel][0], Wk_[mt][nt][2 * sel][1],
                                         Wk_[mt][nt][2 * sel + 1][0], Wk_[mt][nt][2 * sel + 1][1], kg);

    stage_write(ldsV, tid, RV);                            // waits RV only
    if (it == 0) stage_issue(keys + base + 64 * D_, tid, RK);
    __syncthreads();  // ldsV(it) ready; everyone past ldsK reads

    gemm_std<true>(ldsV, WfV, w, lo, kg, acc);
    // V epilogue -> words -> frags
    unsigned Wv_[2][2][4][2];
#pragma unroll
    for (int mt = 0; mt < 2; ++mt)
#pragma unroll
      for (int nt = 0; nt < 2; ++nt) {
        const float bias = nt ? bv1 : bv0;
#pragma unroll
        for (int q = 0; q < 4; ++q) {
          float vv[4];
#pragma unroll
          for (int c = 0; c < 4; ++c) {
            const int tok = it * 64 + 32 * mt + 8 * q + 4 * kg + c;
            vv[c] = (acc[mt][nt][4 * q + c] + bias) * ldsM[tok];
          }
          Wv_[mt][nt][q][0] = pack2(vv[0], vv[1]);
          Wv_[mt][nt][q][1] = pack2(vv[2], vv[3]);
        }
      }
    short8 vf[2][4];
#pragma unroll
    for (int nt = 0; nt < 2; ++nt)
#pragma unroll
      for (int mt = 0; mt < 2; ++mt)
#pragma unroll
        for (int sel = 0; sel < 2; ++sel)
          vf[nt][2 * mt + sel] = mk_frag(Wv_[mt][nt][2 * sel][0], Wv_[mt][nt][2 * sel][1],
                                         Wv_[mt][nt][2 * sel + 1][0], Wv_[mt][nt][2 * sel + 1][1], kg);
    if (it == 0) stage_issue(values + base + 64 * D_, tid, RV);

    // KV[d][m] += kf^T v   (A rows = d = lo, B cols = m = lo, k = tok)
#pragma unroll
    for (int hh = 0; hh < 2; ++hh)
#pragma unroll
      for (int tg = 0; tg < 4; ++tg)
        kvacc[hh] = __builtin_amdgcn_mfma_f32_32x32x16_bf16(kf[hh][tg], vf[hh][tg],
                                                            kvacc[hh], 0, 0, 0);
    if (it == 0) stage_write(ldsK, tid, RK);  // safe: all waves past ldsK reads
  }

  // ---- flush ----
  const float tot0 = ks0 + __shfl_xor(ks0, 32);
  const float tot1 = ks1 + __shfl_xor(ks1, 32);
  if (use_atomic) {
    atomicAdd(&Ksum[b * 256 + w * 64 + kg * 32 + lo], kg ? tot1 : tot0);
#pragma unroll
    for (int hh = 0; hh < 2; ++hh) {
      const int h = 2 * w + hh;
#pragma unroll
      for (int r = 0; r < 16; ++r) {
        const int d = (r & 3) + 8 * (r >> 2) + 4 * kg;
        atomicAdd(&KV[(((size_t)b * H_ + h) * 32 + lo) * 32 + d], kvacc[hh][r]);
      }
    }
  } else {
    kspart[((size_t)b * 64 + blk) * 256 + w * 64 + kg * 32 + lo] = kg ? tot1 : tot0;
#pragma unroll
    for (int hh = 0; hh < 2; ++hh) {
      const int h = 2 * w + hh;
      float* dst = kvpart + ((size_t)b * 64 + blk) * 8192 + ((h * 2 + kg) * 16) * 32 + lo;
#pragma unroll
      for (int r = 0; r < 16; ++r) dst[r * 32] = kvacc[hh][r];
    }
  }
}

// kR: reduce 64 block-partials per batch. grid 264 x 256.
__global__ void kR(const float* __restrict__ kvpart, const float* __restrict__ kspart,
                   float* __restrict__ KV, float* __restrict__ Ksum) {
  int idx = blockIdx.x * 256 + threadIdx.x;
  if (idx < 65536) {
    int b = idx >> 13, r2 = idx & 8191;
    int h = r2 >> 10, kg2 = (r2 >> 9) & 1, rr = (r2 >> 5) & 15, m = r2 & 31;
    const float* p = kvpart + (size_t)b * 64 * 8192 + r2;
    float s = 0.f;
#pragma unroll 8
    for (int j = 0; j < 64; ++j) s += p[(size_t)j * 8192];
    int d = (rr & 3) + 4 * kg2 + 8 * (rr >> 2);
    KV[(((size_t)b * H_ + h) * 32 + m) * 32 + d] = s;
  } else if (idx < 67584) {
    int t = idx - 65536;
    int b = t >> 8, o = t & 255;
    const float* p = kspart + (size_t)b * 64 * 256 + o;
    float s = 0.f;
#pragma unroll 8
    for (int j = 0; j < 64; ++j) s += p[j * 256];
    Ksum[t] = s;
  }
}

// kB: Q projection + feature map + num/Z + output GEMM. grid (64, B_), 256 thr.
__global__ void __launch_bounds__(256, 2)
kB(const float* __restrict__ queries, const float* __restrict__ qmask,
   const float* __restrict__ bq, const float* __restrict__ bm,
   const short8* __restrict__ WfQ, const short8* __restrict__ WfM,
   const float* __restrict__ KV, const float* __restrict__ Ksum,
   float* __restrict__ out) {
  extern __shared__ char lds[];
  char* ldsQ = lds + KB_Q;
  char* ldsO = lds + KB_O;
  float* ldsM = (float*)(lds + KB_M);
  float* ldsS = (float*)(lds + KB_S);
  float* ldsBq = (float*)(lds + KB_BQ);
  const int tid = threadIdx.x, w = tid >> 6, lane = tid & 63, lo = lane & 31, kg = lane >> 5;
  const int blk = blockIdx.x, b = blockIdx.y;
  const size_t base = ((size_t)b * S_ + blk * 128) * D_;

  ldsS[tid] = Ksum[b * 256 + tid];
  ldsBq[tid] = bq[tid];
  if (tid < 128) ldsM[tid] = qmask[(size_t)b * S_ + blk * 128 + tid];
  const float bm0 = bm[w * 64 + lo], bm1 = bm[w * 64 + 32 + lo];

  // hoist KV fragments for this wave's two heads (A-frag: row m = lo, k = d)
  short8 kvf[2][2];
#pragma unroll
  for (int hh = 0; hh < 2; ++hh)
#pragma unroll
    for (int ksd = 0; ksd < 2; ++ksd) {
      const float* p = KV + (((size_t)b * H_ + 2 * w + hh) * 32 + lo) * 32 + ksd * 16 + kg * 8;
      float4 x0 = *(const float4*)p, x1 = *(const float4*)(p + 4);
      union { unsigned u[4]; short8 s8; } t;
      t.u[0] = pack2(x0.x, x0.y); t.u[1] = pack2(x0.z, x0.w);
      t.u[2] = pack2(x1.x, x1.y); t.u[3] = pack2(x1.z, x1.w);
      kvf[hh][ksd] = t.s8;
    }

  float4 RQ[16];
  stage_issue(queries + base, tid, RQ);
  stage_write(ldsQ, tid, RQ);

#pragma unroll
  for (int it = 0; it < 2; ++it) {
    __syncthreads();  // ldsQ(it) + lds smalls visible
    f32x16 qa[2][2];
    gemm_flip(ldsQ, WfQ, w, lo, kg, qa);
    if (it == 0) stage_issue(queries + base + 64 * D_, tid, RQ);

    // Q epilogue: bias + elu+1 + qmask -> words; Z via in-register dot
    unsigned Wq_[2][2][4][2];
    float inv_[2][2];
#pragma unroll
    for (int At = 0; At < 2; ++At) {
      float kss[4][4], bql[4][4];
#pragma unroll
      for (int q = 0; q < 4; ++q)
#pragma unroll
        for (int c = 0; c < 4; ++c) {
          const int o = w * 64 + At * 32 + 8 * q + 4 * kg + c;
          kss[q][c] = ldsS[o];
          bql[q][c] = ldsBq[o];
        }
#pragma unroll
      for (int Bt = 0; Bt < 2; ++Bt) {
        const float qm = ldsM[it * 64 + Bt * 32 + lo];
        float z = 0.f;
#pragma unroll
        for (int q = 0; q < 4; ++q) {
          float vv[4];
#pragma unroll
          for (int c = 0; c < 4; ++c) {
            float f = qa[At][Bt][4 * q + c] + bql[q][c];
            f = f > 0.f ? f + 1.f : __expf(f);
            f *= qm;
            z += f * kss[q][c];
            vv[c] = f;
          }
          Wq_[At][Bt][q][0] = pack2(vv[0], vv[1]);
          Wq_[At][Bt][q][1] = pack2(vv[2], vv[3]);
        }
        const float zf = z + __shfl_xor(z, 32);
        inv_[At][Bt] = 1.0f / (zf + EPS_);
      }
    }

    // num = KV x qf (D[m][tok]); vo = num/Z -> voF chunks in ldsO
#pragma unroll
    for (int hh = 0; hh < 2; ++hh) {
      const int h = 2 * w + hh;
#pragma unroll
      for (int Bt = 0; Bt < 2; ++Bt) {
        f32x16 pn;
#pragma unroll
        for (int i = 0; i < 16; ++i) pn[i] = 0.f;
#pragma unroll
        for (int ksd = 0; ksd < 2; ++ksd) {
          short8 qf = mk_frag(Wq_[hh][Bt][2 * ksd][0], Wq_[hh][Bt][2 * ksd][1],
                              Wq_[hh][Bt][2 * ksd + 1][0], Wq_[hh][Bt][2 * ksd + 1][1], kg);
          pn = __builtin_amdgcn_mfma_f32_32x32x16_bf16(kvf[hh][ksd], qf, pn, 0, 0, 0);
        }
        const float inv = inv_[hh][Bt];
        const int tok = Bt * 32 + lo;
#pragma unroll
        for (int q = 0; q < 4; ++q)
          *(ushort4*)(ldsO + ((h * 4 + q) * 64 + tok) * 16 + kg * 8) =
              make_ushort4(f2bf(pn[4 * q + 0] * inv), f2bf(pn[4 * q + 1] * inv),
                           f2bf(pn[4 * q + 2] * inv), f2bf(pn[4 * q + 3] * inv));
      }
    }
    __syncthreads();  // voF complete

    f32x16 oa[2][2];
    gemm_std<false>(ldsO, WfM, w, lo, kg, oa);
    if (it == 0) stage_write(ldsQ, tid, RQ);  // safe: all past ldsQ reads

    const int t0 = blk * 128 + it * 64;
#pragma unroll
    for (int mt = 0; mt < 2; ++mt)
#pragma unroll
      for (int nt = 0; nt < 2; ++nt) {
        const float bias = nt ? bm1 : bm0;
        const int o = w * 64 + nt * 32 + lo;
        float* dst = out + ((size_t)b * S_ + t0 + 32 * mt) * D_ + o;
#pragma unroll
        for (int r = 0; r < 16; ++r) {
          const int tok = (r & 3) + 8 * (r >> 2) + 4 * kg;
          dst[(size_t)tok * D_] = oa[mt][nt][r] + bias;
        }
      }
  }
}

extern "C" void kernel_launch(void* const* d_in, const int* in_sizes, int n_in,
                              void* d_out, int out_size, void* d_ws, size_t ws_size,
                              hipStream_t stream) {
  const float* queries = (const float*)d_in[0];
  const float* keys    = (const float*)d_in[1];
  const float* values  = (const float*)d_in[2];
  const float* qmask   = (const float*)d_in[3];
  const float* kmask   = (const float*)d_in[4];
  const float* Wq = (const float*)d_in[5];
  const float* bq = (const float*)d_in[6];
  const float* Wk = (const float*)d_in[7];
  const float* bk = (const float*)d_in[8];
  const float* Wv = (const float*)d_in[9];
  const float* bv = (const float*)d_in[10];
  const float* Wm = (const float*)d_in[11];
  const float* bm = (const float*)d_in[12];
  float* out = (float*)d_out;

  char* ws = (char*)d_ws;
  unsigned short* Wf = (unsigned short*)ws;          // 512KB
  float* KV   = (float*)(ws + 524288);               // 256KB
  float* Ksum = (float*)(ws + 786432);               // 8KB
  float* kvpart = (float*)(ws + 1048576);            // 16MB
  float* kspart = (float*)(ws + 1048576 + 16777216); // 512KB
  const size_t need = 1048576 + 16777216 + 524288;
  const int use_atomic = (ws_size < need) ? 1 : 0;

  hipFuncSetAttribute(reinterpret_cast<const void*>(kA),
                      hipFuncAttributeMaxDynamicSharedMemorySize, KA_BYTES);
  hipFuncSetAttribute(reinterpret_cast<const void*>(kB),
                      hipFuncAttributeMaxDynamicSharedMemorySize, KB_BYTES);

  kPrep<<<128, 256, 0, stream>>>(Wq, Wk, Wv, Wm, Wf);
  if (use_atomic) hipMemsetAsync(ws + 524288, 0, 262144 + 8192, stream);

  const short8* Wf8 = (const short8*)Wf;
  kA<<<dim3(64, B_), 256, KA_BYTES, stream>>>(keys, values, kmask, bk, bv,
      Wf8 + (size_t)1 * 8192, Wf8 + (size_t)2 * 8192, kvpart, kspart, KV, Ksum, use_atomic);
  if (!use_atomic) kR<<<264, 256, 0, stream>>>(kvpart, kspart, KV, Ksum);
  kB<<<dim3(64, B_), 256, KB_BYTES, stream>>>(queries, qmask, bq, bm,
      Wf8, Wf8 + (size_t)3 * 8192, KV, Ksum, out);
}